// Round 1
// baseline (659.297 us; speedup 1.0000x reference)
//
#include <hip/hip_runtime.h>
#include <math.h>

#define NEG_BIAS_F (-1.0e9f)

constexpr int Bc = 8;     // batch
constexpr int Lc = 2048;  // context length
constexpr int Lq = 512;   // query length
constexpr int D  = 512;   // feature dim
constexpr int CCH = 128;          // rows per column-softmax chunk
constexpr int NCH = Lc / CCH;     // 16 chunks

// ---------------------------------------------------------------------------
// Tiled fp32 GEMM. TRANS: 0 = NN (A[M,K], B[K,N]); 1 = NT (B is [N,K]);
// 2 = TN (A is [K,M]). EPI adds rowBias + colBias + mask bias (for S).
// Block: 256 threads, each computes (BM/16)x(BN/16) outputs via float4 LDS reads.
// All dims must be multiples of BM/BN/16 (true for this problem).
// ---------------------------------------------------------------------------
template<int TRANS, int BM, int BN, bool EPI>
__global__ __launch_bounds__(256)
void gemm_f32(const float* __restrict__ A, const float* __restrict__ Bm,
              float* __restrict__ C,
              int M, int N, int K, int lda, int ldb, int ldc,
              long bA, long bB, long bC,
              const float* __restrict__ rowBias, const float* __restrict__ colBias,
              const int* __restrict__ mask, long bMask)
{
    constexpr int BK = 16;
    constexpr int RM = BM / 16, RN = BN / 16;
    __shared__ float As[BK][BM + 4];
    __shared__ float Bs[BK][BN + 4];
    const int bz = blockIdx.z;
    A  += (long)bz * bA;
    Bm += (long)bz * bB;
    C  += (long)bz * bC;
    const int m0 = blockIdx.y * BM, n0 = blockIdx.x * BN;
    const int tid = threadIdx.x, tx = tid & 15, ty = tid >> 4;
    float acc[RM][RN] = {};

    for (int k0 = 0; k0 < K; k0 += BK) {
        // ---- stage A tile into As[k][m] ----
        if constexpr (TRANS == 2) {
            // A is [K,M], contiguous along m -> vector stores
            #pragma unroll
            for (int idx = tid; idx < BK * (BM / 4); idx += 256) {
                int k = idx / (BM / 4), m4 = idx % (BM / 4);
                float4 v = *(const float4*)&A[(long)(k0 + k) * lda + m0 + m4 * 4];
                *(float4*)&As[k][m4 * 4] = v;
            }
        } else {
            // A is [M,K], contiguous along k -> load float4, scalar-transpose store
            #pragma unroll
            for (int idx = tid; idx < (BK / 4) * BM; idx += 256) {
                int i = idx >> 2, j4 = idx & 3;
                float4 v = *(const float4*)&A[(long)(m0 + i) * lda + k0 + j4 * 4];
                As[j4 * 4 + 0][i] = v.x; As[j4 * 4 + 1][i] = v.y;
                As[j4 * 4 + 2][i] = v.z; As[j4 * 4 + 3][i] = v.w;
            }
        }
        // ---- stage B tile into Bs[k][n] ----
        if constexpr (TRANS == 1) {
            // B is [N,K], contiguous along k
            #pragma unroll
            for (int idx = tid; idx < (BK / 4) * BN; idx += 256) {
                int i = idx >> 2, j4 = idx & 3;
                float4 v = *(const float4*)&Bm[(long)(n0 + i) * ldb + k0 + j4 * 4];
                Bs[j4 * 4 + 0][i] = v.x; Bs[j4 * 4 + 1][i] = v.y;
                Bs[j4 * 4 + 2][i] = v.z; Bs[j4 * 4 + 3][i] = v.w;
            }
        } else {
            // B is [K,N], contiguous along n -> vector stores
            #pragma unroll
            for (int idx = tid; idx < BK * (BN / 4); idx += 256) {
                int k = idx / (BN / 4), n4 = idx % (BN / 4);
                float4 v = *(const float4*)&Bm[(long)(k0 + k) * ldb + n0 + n4 * 4];
                *(float4*)&Bs[k][n4 * 4] = v;
            }
        }
        __syncthreads();

        #pragma unroll
        for (int k = 0; k < BK; ++k) {
            float a[RM], b[RN];
            #pragma unroll
            for (int g = 0; g < RM / 4; ++g) {
                float4 v = *(const float4*)&As[k][g * 64 + ty * 4];
                a[g * 4 + 0] = v.x; a[g * 4 + 1] = v.y;
                a[g * 4 + 2] = v.z; a[g * 4 + 3] = v.w;
            }
            #pragma unroll
            for (int g = 0; g < RN / 4; ++g) {
                float4 v = *(const float4*)&Bs[k][g * 64 + tx * 4];
                b[g * 4 + 0] = v.x; b[g * 4 + 1] = v.y;
                b[g * 4 + 2] = v.z; b[g * 4 + 3] = v.w;
            }
            #pragma unroll
            for (int i = 0; i < RM; ++i)
                #pragma unroll
                for (int j = 0; j < RN; ++j)
                    acc[i][j] = fmaf(a[i], b[j], acc[i][j]);
        }
        __syncthreads();
    }

    // ---- store (float4 along n) ----
    #pragma unroll
    for (int i = 0; i < RM; ++i) {
        int r = m0 + (i / 4) * 64 + ty * 4 + (i & 3);
        #pragma unroll
        for (int jg = 0; jg < RN / 4; ++jg) {
            int c = n0 + jg * 64 + tx * 4;
            float4 v;
            v.x = acc[i][jg * 4 + 0]; v.y = acc[i][jg * 4 + 1];
            v.z = acc[i][jg * 4 + 2]; v.w = acc[i][jg * 4 + 3];
            if constexpr (EPI) {
                float rb = rowBias[(long)bz * M + r];
                float4 cb = *(const float4*)&colBias[(long)bz * N + c];
                int4 mk = *(const int4*)&mask[(long)bz * bMask + (long)r * N + c];
                v.x += rb + cb.x + (mk.x ? 0.f : NEG_BIAS_F);
                v.y += rb + cb.y + (mk.y ? 0.f : NEG_BIAS_F);
                v.z += rb + cb.z + (mk.z ? 0.f : NEG_BIAS_F);
                v.w += rb + cb.w + (mk.w ? 0.f : NEG_BIAS_F);
            }
            *(float4*)&C[(long)r * ldc + c] = v;
        }
    }
}

// ---------------------------------------------------------------------------
// cw / qw: one wave per row, 512-length dot product with a [D,1] weight.
// ---------------------------------------------------------------------------
__global__ __launch_bounds__(256)
void rowdot(const float* __restrict__ X, const float* __restrict__ w,
            float* __restrict__ outv, long rows)
{
    long wv = (long)blockIdx.x * 4 + (threadIdx.x >> 6);
    int lane = threadIdx.x & 63;
    if (wv >= rows) return;
    const float4* xr = (const float4*)(X + wv * D);
    const float4* wr = (const float4*)w;
    float4 a0 = xr[lane * 2], a1 = xr[lane * 2 + 1];
    float4 b0 = wr[lane * 2], b1 = wr[lane * 2 + 1];
    float s = a0.x * b0.x + a0.y * b0.y + a0.z * b0.z + a0.w * b0.w
            + a1.x * b1.x + a1.y * b1.y + a1.z * b1.z + a1.w * b1.w;
    #pragma unroll
    for (int off = 32; off; off >>= 1) s += __shfl_xor(s, off);
    if (lane == 0) outv[wv] = s;
}

// ---------------------------------------------------------------------------
// Row softmax (over Lq=512, contiguous), in place. One wave per row.
// ---------------------------------------------------------------------------
__global__ __launch_bounds__(256)
void row_softmax(float* __restrict__ S, long rows)
{
    long wv = (long)blockIdx.x * 4 + (threadIdx.x >> 6);
    int lane = threadIdx.x & 63;
    if (wv >= rows) return;
    float4* row = (float4*)(S + wv * Lq);
    float4 v0 = row[lane * 2], v1 = row[lane * 2 + 1];
    float m = fmaxf(fmaxf(fmaxf(v0.x, v0.y), fmaxf(v0.z, v0.w)),
                    fmaxf(fmaxf(v1.x, v1.y), fmaxf(v1.z, v1.w)));
    #pragma unroll
    for (int off = 32; off; off >>= 1) m = fmaxf(m, __shfl_xor(m, off));
    v0.x = __expf(v0.x - m); v0.y = __expf(v0.y - m);
    v0.z = __expf(v0.z - m); v0.w = __expf(v0.w - m);
    v1.x = __expf(v1.x - m); v1.y = __expf(v1.y - m);
    v1.z = __expf(v1.z - m); v1.w = __expf(v1.w - m);
    float s = v0.x + v0.y + v0.z + v0.w + v1.x + v1.y + v1.z + v1.w;
    #pragma unroll
    for (int off = 32; off; off >>= 1) s += __shfl_xor(s, off);
    float r = 1.0f / s;
    v0.x *= r; v0.y *= r; v0.z *= r; v0.w *= r;
    v1.x *= r; v1.y *= r; v1.z *= r; v1.w *= r;
    row[lane * 2] = v0; row[lane * 2 + 1] = v1;
}

// ---------------------------------------------------------------------------
// Column softmax (over Lc), phase 1: per-(b, 128-row-chunk, q) online max/sum.
// Thread j handles column q0+j -> coalesced across threads at every c step.
// ---------------------------------------------------------------------------
__global__ __launch_bounds__(256)
void col_softmax_partial(const float* __restrict__ S, float* __restrict__ Pmax,
                         float* __restrict__ Psum)
{
    int b = blockIdx.z, ch = blockIdx.y;
    int q = blockIdx.x * 256 + threadIdx.x;
    const float* base = S + ((long)b * Lc + (long)ch * CCH) * Lq + q;
    float m = -INFINITY, s = 0.f;
    for (int c = 0; c < CCH; ++c) {
        float x = base[(long)c * Lq];
        float nm = fmaxf(m, x);
        s = s * __expf(m - nm) + __expf(x - nm);
        m = nm;
    }
    long o = ((long)b * NCH + ch) * Lq + q;
    Pmax[o] = m;
    Psum[o] = s;
}

__global__ __launch_bounds__(256)
void col_softmax_merge(const float* __restrict__ Pmax, const float* __restrict__ Psum,
                       float* __restrict__ Fmax, float* __restrict__ Frinv)
{
    int i = blockIdx.x * 256 + threadIdx.x;  // b*Lq + q
    if (i >= Bc * Lq) return;
    int b = i >> 9, q = i & (Lq - 1);
    const float* pm = Pmax + (long)b * NCH * Lq + q;
    const float* ps = Psum + (long)b * NCH * Lq + q;
    float m = -INFINITY;
    #pragma unroll
    for (int ch = 0; ch < NCH; ++ch) m = fmaxf(m, pm[ch * Lq]);
    float s = 0.f;
    #pragma unroll
    for (int ch = 0; ch < NCH; ++ch) s += ps[ch * Lq] * __expf(pm[ch * Lq] - m);
    Fmax[i] = m;
    Frinv[i] = 1.0f / s;
}

__global__ __launch_bounds__(256)
void q2c_write(const float* __restrict__ S, const float* __restrict__ Fmax,
               const float* __restrict__ Frinv, float* __restrict__ Q2C)
{
    long idx = (long)blockIdx.x * 256 + threadIdx.x;   // one float4
    long e = idx * 4;
    int q = (int)(e & (Lq - 1));
    long bc = e >> 9;          // b*Lc + c
    int b = (int)(bc >> 11);   // Lc = 2048
    float4 x = ((const float4*)S)[idx];
    const float4 mm = *(const float4*)&Fmax[(long)b * Lq + q];
    const float4 rr = *(const float4*)&Frinv[(long)b * Lq + q];
    float4 o;
    o.x = __expf(x.x - mm.x) * rr.x;
    o.y = __expf(x.y - mm.y) * rr.y;
    o.z = __expf(x.z - mm.z) * rr.z;
    o.w = __expf(x.w - mm.w) * rr.w;
    ((float4*)Q2C)[idx] = o;
}

// ---------------------------------------------------------------------------
// Final assembly: out[:,0:D]=ctx; out[:,2D:3D]=ctx*out[:,D:2D];
// out[:,3D:4D]=ctx*out[:,3D:4D] (slice 3D:4D holds raw qtc from the GEMM).
// ---------------------------------------------------------------------------
__global__ __launch_bounds__(256)
void finalize(const float* __restrict__ ctx, float* __restrict__ out)
{
    long idx = (long)blockIdx.x * 256 + threadIdx.x;  // one float4 along d
    long row = idx / (D / 4);
    int d4 = (int)(idx % (D / 4));
    const float4* cr = (const float4*)(ctx + row * D);
    float4* orow = (float4*)(out + row * 4 * D);
    float4 cx = cr[d4];
    float4 a = orow[(D / 4) + d4];
    float4 b = orow[3 * (D / 4) + d4];
    orow[d4] = cx;
    float4 p;
    p.x = cx.x * a.x; p.y = cx.y * a.y; p.z = cx.z * a.z; p.w = cx.w * a.w;
    orow[2 * (D / 4) + d4] = p;
    float4 r;
    r.x = cx.x * b.x; r.y = cx.y * b.y; r.z = cx.z * b.z; r.w = cx.w * b.w;
    orow[3 * (D / 4) + d4] = r;
}

extern "C" void kernel_launch(void* const* d_in, const int* in_sizes, int n_in,
                              void* d_out, int out_size, void* d_ws, size_t ws_size,
                              hipStream_t stream)
{
    const float* context = (const float*)d_in[0];
    const float* query   = (const float*)d_in[1];
    const int*   mask    = (const int*)d_in[2];
    const float* qWt     = (const float*)d_in[3];
    const float* cWt     = (const float*)d_in[4];
    const float* dotW    = (const float*)d_in[5];
    float* out = (float*)d_out;

    float* ws = (float*)d_ws;
    float* Abuf = ws;  ws += (size_t)Bc * Lc * D;    // 32 MB, reused as T later
    float* S    = ws;  ws += (size_t)Bc * Lc * Lq;   // 32 MB, becomes c2q in place
    float* Q2C  = ws;  ws += (size_t)Bc * Lc * Lq;   // 32 MB
    float* cw   = ws;  ws += (size_t)Bc * Lc;
    float* qw   = ws;  ws += (size_t)Bc * Lq;
    float* Pmax = ws;  ws += (size_t)Bc * NCH * Lq;
    float* Psum = ws;  ws += (size_t)Bc * NCH * Lq;
    float* Fmax = ws;  ws += (size_t)Bc * Lq;
    float* Frinv= ws;  ws += (size_t)Bc * Lq;
    float* T = Abuf;   // Abuf is dead after S is computed

    // 1) A = context @ dot_weights   (M=B*Lc=16384, N=K=512), batch-free
    gemm_f32<0, 128, 128, false><<<dim3(D / 128, (Bc * Lc) / 128, 1), 256, 0, stream>>>(
        context, dotW, Abuf, Bc * Lc, D, D, D, D, D,
        0, 0, 0, nullptr, nullptr, nullptr, 0);

    // 2) cw = context @ context_weights ; qw = query @ query_weights
    rowdot<<<dim3((Bc * Lc) / 4), 256, 0, stream>>>(context, cWt, cw, (long)Bc * Lc);
    rowdot<<<dim3((Bc * Lq) / 4), 256, 0, stream>>>(query, qWt, qw, (long)Bc * Lq);

    // 3) S = A @ query^T + cw + qw + mask bias   (batched NT)
    gemm_f32<1, 128, 128, true><<<dim3(Lq / 128, Lc / 128, Bc), 256, 0, stream>>>(
        Abuf, query, S, Lc, Lq, D, D, D, Lq,
        (long)Lc * D, (long)Lq * D, (long)Lc * Lq, cw, qw, mask, (long)Lc * Lq);

    // 4) column softmax (over Lc) -> Q2C
    col_softmax_partial<<<dim3(Lq / 256, NCH, Bc), 256, 0, stream>>>(S, Pmax, Psum);
    col_softmax_merge<<<dim3((Bc * Lq + 255) / 256), 256, 0, stream>>>(Pmax, Psum, Fmax, Frinv);
    q2c_write<<<dim3((int)(((long)Bc * Lc * Lq / 4) / 256)), 256, 0, stream>>>(S, Fmax, Frinv, Q2C);

    // 5) row softmax (over Lq) in place: S -> c2q
    row_softmax<<<dim3((Bc * Lc) / 4), 256, 0, stream>>>(S, (long)Bc * Lc);

    // 6) ctq = c2q @ query -> out[:, :, D:2D]
    gemm_f32<0, 128, 128, false><<<dim3(D / 128, Lc / 128, Bc), 256, 0, stream>>>(
        S, query, out + D, Lc, D, Lq, Lq, D, 4 * D,
        (long)Lc * Lq, (long)Lq * D, (long)Lc * 4 * D, nullptr, nullptr, nullptr, 0);

    // 7) T = q2c^T @ context   (TN: M=Lq, N=D, K=Lc)
    gemm_f32<2, 64, 64, false><<<dim3(D / 64, Lq / 64, Bc), 256, 0, stream>>>(
        Q2C, context, T, Lq, D, Lc, Lq, D, D,
        (long)Lc * Lq, (long)Lc * D, (long)Lq * D, nullptr, nullptr, nullptr, 0);

    // 8) qtc = c2q @ T -> out[:, :, 3D:4D] (raw, multiplied by ctx in finalize)
    gemm_f32<0, 128, 128, false><<<dim3(D / 128, Lc / 128, Bc), 256, 0, stream>>>(
        S, T, out + 3 * D, Lc, D, Lq, Lq, D, 4 * D,
        (long)Lc * Lq, (long)Lq * D, (long)Lc * 4 * D, nullptr, nullptr, nullptr, 0);

    // 9) finalize
    finalize<<<dim3((int)(((long)Bc * Lc * (D / 4)) / 256)), 256, 0, stream>>>(context, out);
}

// Round 4
// 247.947 us; speedup vs baseline: 2.6590x; 2.6590x over previous
//
#include <hip/hip_runtime.h>
#include <math.h>

#define NEG_BIAS_F (-1.0e9f)

typedef float  f32x4  __attribute__((ext_vector_type(4)));
typedef __bf16 bf16x8 __attribute__((ext_vector_type(8)));
typedef short  s16x8  __attribute__((ext_vector_type(8)));
using u16 = unsigned short;

constexpr int Bc = 8, Lc = 2048, Lq = 512, D = 512;
constexpr int CCH = 128, NCH = Lc / CCH;

__device__ __forceinline__ u16 f2bf(float x) {
    unsigned u = __float_as_uint(x);
    u += 0x7fffu + ((u >> 16) & 1u);
    return (u16)(u >> 16);
}
__device__ __forceinline__ float bf2f(u16 h) { return __uint_as_float((unsigned)h << 16); }

// async global->LDS, 16B per lane; LDS dest must be wave-uniform base (+lane*16 by HW)
__device__ __forceinline__ void gload16(const u16* g, u16* lds) {
    __builtin_amdgcn_global_load_lds(
        (const __attribute__((address_space(1))) void*)g,
        (__attribute__((address_space(3))) void*)lds, 16, 0, 0);
}

__device__ __forceinline__ f32x4 mfma16(s16x8 a, s16x8 b, f32x4 c) {
    return __builtin_amdgcn_mfma_f32_16x16x32_bf16(
        __builtin_bit_cast(bf16x8, a), __builtin_bit_cast(bf16x8, b), c, 0, 0, 0);
}

// ---------------------------------------------------------------------------
// MFMA NT GEMM: C[m,n] = sum_k A[m,k]*B[n,k], A/B bf16 (optionally hi+lo split,
// 3-MFMA compensated product). 128x128 tile, BK=32, 4 waves (2x2 of 64x64).
// EPI: 0 fp32->C1; 1 S-epilogue (+rowB+colB+mask bias) fp32->C1;
//      2 bf16->Cb; 3 split bf16 -> Cb,Cb2;
//      4 out[0:D]=ctx, out[D:2D]=v, out[2D:3D]=ctx*v (C1 = out row base, aux1=ctx);
//      5 C1 = ctx*v (aux1=ctx).
// Requires M%128==0, N%128==0, K%32==0, lda=ldb=K (packed).
// ---------------------------------------------------------------------------
template<bool SPLIT, int EPI>
__global__ __launch_bounds__(256)
void gemm_mfma(const u16* __restrict__ Ah, const u16* __restrict__ Al,
               const u16* __restrict__ Bh, const u16* __restrict__ Bl,
               float* __restrict__ C1, u16* __restrict__ Cb, u16* __restrict__ Cb2,
               int M, int N, int K,
               long sA, long sB, long sC, int ldc,
               const float* __restrict__ aux1, const float* __restrict__ aux2,
               const int* __restrict__ maskp, long sAux)
{
    constexpr int NB = SPLIT ? 4 : 2;
    __shared__ __align__(16) u16 sm[NB * 4096];
    u16* AsH = sm;
    u16* BsH = sm + 4096;
    u16* AsL = sm + (SPLIT ? 8192 : 0);
    u16* BsL = sm + (SPLIT ? 12288 : 0);

    const int bz = blockIdx.z;
    const u16* pAh = Ah + (long)bz * sA;
    const u16* pBh = Bh + (long)bz * sB;
    const u16* pAl = SPLIT ? (Al + (long)bz * sA) : nullptr;
    const u16* pBl = SPLIT ? (Bl + (long)bz * sB) : nullptr;

    const int m0 = blockIdx.y * 128, n0 = blockIdx.x * 128;
    const int tid = threadIdx.x, wid = tid >> 6, lane = tid & 63;
    const int wrow = (wid >> 1) * 64, wcol = (wid & 1) * 64;

    // staging geometry: linear16 = r*256 + wid*64 + lane
    const int srow = wid * 16 + (lane >> 2);   // + r*64 -> tile row
    const int skel = (lane & 3) * 8;           // k element offset
    const int sldo = wid * 512;                // + r*2048 -> LDS element offset (wave-uniform)

    f32x4 acc[4][4] = {};

    for (int k0 = 0; k0 < K; k0 += 32) {
        #pragma unroll
        for (int r = 0; r < 2; ++r) {
            const long goA = (long)(m0 + srow + r * 64) * K + k0 + skel;
            const long goB = (long)(n0 + srow + r * 64) * K + k0 + skel;
            const int lo = sldo + r * 2048;
            gload16(pAh + goA, AsH + lo);
            gload16(pBh + goB, BsH + lo);
            if (SPLIT) {
                gload16(pAl + goA, AsL + lo);
                gload16(pBl + goB, BsL + lo);
            }
        }
        __syncthreads();

        s16x8 a[4], b[4], al[4], bl[4];
        #pragma unroll
        for (int f = 0; f < 4; ++f) {
            const int ra = (wrow + f * 16 + (lane & 15)) * 32 + (lane >> 4) * 8;
            const int rb = (wcol + f * 16 + (lane & 15)) * 32 + (lane >> 4) * 8;
            a[f] = *(const s16x8*)&AsH[ra];
            b[f] = *(const s16x8*)&BsH[rb];
            if (SPLIT) { al[f] = *(const s16x8*)&AsL[ra]; bl[f] = *(const s16x8*)&BsL[rb]; }
        }
        #pragma unroll
        for (int i = 0; i < 4; ++i)
            #pragma unroll
            for (int j = 0; j < 4; ++j) {
                acc[i][j] = mfma16(a[i], b[j], acc[i][j]);
                if (SPLIT) {
                    acc[i][j] = mfma16(a[i], bl[j], acc[i][j]);
                    acc[i][j] = mfma16(al[i], b[j], acc[i][j]);
                }
            }
        __syncthreads();
    }

    // C/D layout (m89-verified): col = lane&15, row = (lane>>4)*4 + reg
    #pragma unroll
    for (int i = 0; i < 4; ++i) {
        #pragma unroll
        for (int r = 0; r < 4; ++r) {
            const int row = m0 + wrow + i * 16 + (lane >> 4) * 4 + r;
            #pragma unroll
            for (int j = 0; j < 4; ++j) {
                const int col = n0 + wcol + j * 16 + (lane & 15);
                float v = acc[i][j][r];
                if constexpr (EPI == 0) {
                    C1[(long)bz * sC + (long)row * ldc + col] = v;
                } else if constexpr (EPI == 1) {
                    v += aux1[(long)bz * M + row] + aux2[(long)bz * N + col];
                    v += maskp[(long)bz * sAux + (long)row * N + col] ? 0.f : NEG_BIAS_F;
                    C1[(long)bz * sC + (long)row * ldc + col] = v;
                } else if constexpr (EPI == 2) {
                    Cb[(long)bz * sC + (long)row * ldc + col] = f2bf(v);
                } else if constexpr (EPI == 3) {
                    u16 h = f2bf(v);
                    Cb[(long)bz * sC + (long)row * ldc + col] = h;
                    Cb2[(long)bz * sC + (long)row * ldc + col] = f2bf(v - bf2f(h));
                } else if constexpr (EPI == 4) {
                    float c = aux1[(long)bz * sAux + (long)row * D + col];
                    float* p = C1 + (long)bz * sC + (long)row * ldc;
                    p[col] = c;
                    p[D + col] = v;
                    p[2 * D + col] = c * v;
                } else {  // 5
                    float c = aux1[(long)bz * sAux + (long)row * D + col];
                    C1[(long)bz * sC + (long)row * ldc + col] = c * v;
                }
            }
        }
    }
}

// ---------------------------------------------------------------------------
// fp32 -> (hi, lo) bf16 split, vectorized
// ---------------------------------------------------------------------------
__global__ __launch_bounds__(256)
void split_bf16(const float* __restrict__ x, u16* __restrict__ hi, u16* __restrict__ lo, long n4)
{
    long i = (long)blockIdx.x * 256 + threadIdx.x;
    if (i >= n4) return;
    float4 v = ((const float4*)x)[i];
    ushort4 h, l;
    h.x = f2bf(v.x); l.x = f2bf(v.x - bf2f(h.x));
    h.y = f2bf(v.y); l.y = f2bf(v.y - bf2f(h.y));
    h.z = f2bf(v.z); l.z = f2bf(v.z - bf2f(h.z));
    h.w = f2bf(v.w); l.w = f2bf(v.w - bf2f(h.w));
    ((ushort4*)hi)[i] = h;
    ((ushort4*)lo)[i] = l;
}

// ---------------------------------------------------------------------------
// LDS-tiled transpose: in fp32 [R,C] -> out bf16 [C,R]. EXPSM applies
// exp(x - Fm[col])*Fr[col] (column softmax finalize) during the transpose.
// ---------------------------------------------------------------------------
template<bool EXPSM>
__global__ __launch_bounds__(256)
void transpose_bf16(const float* __restrict__ in, u16* __restrict__ out,
                    int R, int C, long sIn, long sOut,
                    const float* __restrict__ Fm, const float* __restrict__ Fr, int Cdim)
{
    __shared__ float t[32][33];
    const int b = blockIdx.z;
    in += (long)b * sIn; out += (long)b * sOut;
    const int r0 = blockIdx.y * 32, c0 = blockIdx.x * 32;
    const int tid = threadIdx.x;
    {
        const int rr = tid >> 3, cc = (tid & 7) * 4;
        float4 v = *(const float4*)&in[(long)(r0 + rr) * C + c0 + cc];
        t[rr][cc] = v.x; t[rr][cc + 1] = v.y; t[rr][cc + 2] = v.z; t[rr][cc + 3] = v.w;
    }
    __syncthreads();
    const int oc = tid >> 3, orr = (tid & 7) * 4;
    float fm = 0.f, fr = 1.f;
    if (EXPSM) { fm = Fm[(long)b * Cdim + c0 + oc]; fr = Fr[(long)b * Cdim + c0 + oc]; }
    float v0 = t[orr + 0][oc], v1 = t[orr + 1][oc], v2 = t[orr + 2][oc], v3 = t[orr + 3][oc];
    if (EXPSM) {
        v0 = __expf(v0 - fm) * fr; v1 = __expf(v1 - fm) * fr;
        v2 = __expf(v2 - fm) * fr; v3 = __expf(v3 - fm) * fr;
    }
    ushort4 o;
    o.x = f2bf(v0); o.y = f2bf(v1); o.z = f2bf(v2); o.w = f2bf(v3);
    *(ushort4*)&out[(long)(c0 + oc) * R + r0 + orr] = o;
}

// ---------------------------------------------------------------------------
// cw / qw: one wave per row, 512-length dot with [D,1] weight
// ---------------------------------------------------------------------------
__global__ __launch_bounds__(256)
void rowdot(const float* __restrict__ X, const float* __restrict__ w,
            float* __restrict__ outv, long rows)
{
    long wv = (long)blockIdx.x * 4 + (threadIdx.x >> 6);
    int lane = threadIdx.x & 63;
    if (wv >= rows) return;
    const float4* xr = (const float4*)(X + wv * D);
    const float4* wr = (const float4*)w;
    float4 a0 = xr[lane * 2], a1 = xr[lane * 2 + 1];
    float4 b0 = wr[lane * 2], b1 = wr[lane * 2 + 1];
    float s = a0.x * b0.x + a0.y * b0.y + a0.z * b0.z + a0.w * b0.w
            + a1.x * b1.x + a1.y * b1.y + a1.z * b1.z + a1.w * b1.w;
    #pragma unroll
    for (int off = 32; off; off >>= 1) s += __shfl_xor(s, off);
    if (lane == 0) outv[wv] = s;
}

// ---------------------------------------------------------------------------
// Row softmax (over Lq=512) -> bf16 out (c2q). One wave per row. S unmodified.
// ---------------------------------------------------------------------------
__global__ __launch_bounds__(256)
void row_softmax_bf16(const float* __restrict__ S, u16* __restrict__ out, long rows)
{
    long wv = (long)blockIdx.x * 4 + (threadIdx.x >> 6);
    int lane = threadIdx.x & 63;
    if (wv >= rows) return;
    const float4* row = (const float4*)(S + wv * Lq);
    float4 v0 = row[lane * 2], v1 = row[lane * 2 + 1];
    float m = fmaxf(fmaxf(fmaxf(v0.x, v0.y), fmaxf(v0.z, v0.w)),
                    fmaxf(fmaxf(v1.x, v1.y), fmaxf(v1.z, v1.w)));
    #pragma unroll
    for (int off = 32; off; off >>= 1) m = fmaxf(m, __shfl_xor(m, off));
    v0.x = __expf(v0.x - m); v0.y = __expf(v0.y - m);
    v0.z = __expf(v0.z - m); v0.w = __expf(v0.w - m);
    v1.x = __expf(v1.x - m); v1.y = __expf(v1.y - m);
    v1.z = __expf(v1.z - m); v1.w = __expf(v1.w - m);
    float s = v0.x + v0.y + v0.z + v0.w + v1.x + v1.y + v1.z + v1.w;
    #pragma unroll
    for (int off = 32; off; off >>= 1) s += __shfl_xor(s, off);
    float r = 1.0f / s;
    ushort4 o0, o1;
    o0.x = f2bf(v0.x * r); o0.y = f2bf(v0.y * r); o0.z = f2bf(v0.z * r); o0.w = f2bf(v0.w * r);
    o1.x = f2bf(v1.x * r); o1.y = f2bf(v1.y * r); o1.z = f2bf(v1.z * r); o1.w = f2bf(v1.w * r);
    *(ushort4*)&out[wv * Lq + lane * 8] = o0;
    *(ushort4*)&out[wv * Lq + lane * 8 + 4] = o1;
}

// ---------------------------------------------------------------------------
// Column softmax (over Lc): per-chunk online max/sum, then merge
// ---------------------------------------------------------------------------
__global__ __launch_bounds__(256)
void col_softmax_partial(const float* __restrict__ S, float* __restrict__ Pmax,
                         float* __restrict__ Psum)
{
    int b = blockIdx.z, ch = blockIdx.y;
    int q = blockIdx.x * 256 + threadIdx.x;
    const float* base = S + ((long)b * Lc + (long)ch * CCH) * Lq + q;
    float m = -INFINITY, s = 0.f;
    for (int c = 0; c < CCH; ++c) {
        float x = base[(long)c * Lq];
        float nm = fmaxf(m, x);
        s = s * __expf(m - nm) + __expf(x - nm);
        m = nm;
    }
    long o = ((long)b * NCH + ch) * Lq + q;
    Pmax[o] = m;
    Psum[o] = s;
}

__global__ __launch_bounds__(256)
void col_softmax_merge(const float* __restrict__ Pmax, const float* __restrict__ Psum,
                       float* __restrict__ Fmax, float* __restrict__ Frinv)
{
    int i = blockIdx.x * 256 + threadIdx.x;
    if (i >= Bc * Lq) return;
    int b = i >> 9, q = i & (Lq - 1);
    const float* pm = Pmax + (long)b * NCH * Lq + q;
    const float* ps = Psum + (long)b * NCH * Lq + q;
    float m = -INFINITY;
    #pragma unroll
    for (int ch = 0; ch < NCH; ++ch) m = fmaxf(m, pm[ch * Lq]);
    float s = 0.f;
    #pragma unroll
    for (int ch = 0; ch < NCH; ++ch) s += ps[ch * Lq] * __expf(pm[ch * Lq] - m);
    Fmax[i] = m;
    Frinv[i] = 1.0f / s;
}

extern "C" void kernel_launch(void* const* d_in, const int* in_sizes, int n_in,
                              void* d_out, int out_size, void* d_ws, size_t ws_size,
                              hipStream_t stream)
{
    const float* context = (const float*)d_in[0];
    const float* query   = (const float*)d_in[1];
    const int*   mask    = (const int*)d_in[2];
    const float* qWt     = (const float*)d_in[3];
    const float* cWt     = (const float*)d_in[4];
    const float* dotW    = (const float*)d_in[5];
    float* out = (float*)d_out;

    char* w = (char*)d_ws;
    size_t off = 0;
    auto alloc = [&](size_t bytes) { void* p = w + off; off += (bytes + 255) & ~(size_t)255; return p; };

    // Region 1 (33.5 MB): ctx hi/lo during pre-softmax; q2cT + c2q after
    u16* ctx_hi = (u16*)alloc((size_t)Bc * Lc * D * 2);
    u16* ctx_lo = (u16*)alloc((size_t)Bc * Lc * D * 2);
    u16* q2cT = ctx_hi;   // [B, Lq, Lc] bf16 (ctx_hi dead after G2)
    u16* c2q  = ctx_lo;   // [B, Lc, Lq] bf16 (ctx_lo dead after G2)
    // Region 2 (33.5 MB): S fp32; after softmax passes reused for ctxT/qT/Tt
    float* S = (float*)alloc((size_t)Bc * Lc * Lq * 4);
    u16* ctxT = (u16*)S;                                        // [B, D, Lc]
    u16* qT   = (u16*)((char*)S + (size_t)Bc * D * Lc * 2);     // [B, D, Lq]
    u16* Tt   = (u16*)((char*)S + (size_t)Bc * D * Lc * 2
                               + (size_t)Bc * D * Lq * 2);      // [B, D, Lq]
    // Fixed region
    u16* q_hi  = (u16*)alloc((size_t)Bc * Lq * D * 2);
    u16* q_lo  = (u16*)alloc((size_t)Bc * Lq * D * 2);
    u16* w_hi  = (u16*)alloc((size_t)D * D * 2);
    u16* w_lo  = (u16*)alloc((size_t)D * D * 2);
    u16* Kt_hi = (u16*)alloc((size_t)Bc * Lq * D * 2);
    u16* Kt_lo = (u16*)alloc((size_t)Bc * Lq * D * 2);
    float* cw   = (float*)alloc((size_t)Bc * Lc * 4);
    float* qw   = (float*)alloc((size_t)Bc * Lq * 4);
    float* Pmax = (float*)alloc((size_t)Bc * NCH * Lq * 4);
    float* Psum = (float*)alloc((size_t)Bc * NCH * Lq * 4);
    float* Fmax = (float*)alloc((size_t)Bc * Lq * 4);
    float* Frin = (float*)alloc((size_t)Bc * Lq * 4);

    // 1) hi/lo splits + bias vectors
    split_bf16<<<dim3((int)((long)Bc * Lc * D / 4 / 256)), 256, 0, stream>>>(
        context, ctx_hi, ctx_lo, (long)Bc * Lc * D / 4);
    split_bf16<<<dim3((int)((long)Bc * Lq * D / 4 / 256)), 256, 0, stream>>>(
        query, q_hi, q_lo, (long)Bc * Lq * D / 4);
    split_bf16<<<dim3(D * D / 4 / 256), 256, 0, stream>>>(dotW, w_hi, w_lo, (long)D * D / 4);
    rowdot<<<dim3(Bc * Lc / 4), 256, 0, stream>>>(context, cWt, cw, (long)Bc * Lc);
    rowdot<<<dim3(Bc * Lq / 4), 256, 0, stream>>>(query, qWt, qw, (long)Bc * Lq);

    // 2) G1: Kt[b] = query_b @ dotW^T  [Lq, D], split-in split-out
    gemm_mfma<true, 3><<<dim3(4, 4, Bc), 256, 0, stream>>>(
        q_hi, q_lo, w_hi, w_lo, nullptr, Kt_hi, Kt_lo,
        Lq, D, D, (long)Lq * D, 0, (long)Lq * D, D,
        nullptr, nullptr, nullptr, 0);

    // 3) G2: S[b] = ctx_b @ Kt_b^T + cw + qw + mask bias  [Lc, Lq] fp32
    gemm_mfma<true, 1><<<dim3(4, 16, Bc), 256, 0, stream>>>(
        ctx_hi, ctx_lo, Kt_hi, Kt_lo, S, nullptr, nullptr,
        Lc, Lq, D, (long)Lc * D, (long)Lq * D, (long)Lc * Lq, Lq,
        cw, qw, mask, (long)Lc * Lq);

    // 4) column softmax stats
    col_softmax_partial<<<dim3(Lq / 256, NCH, Bc), 256, 0, stream>>>(S, Pmax, Psum);
    col_softmax_merge<<<dim3((Bc * Lq + 255) / 256), 256, 0, stream>>>(Pmax, Psum, Fmax, Frin);

    // 5) q2cT[b] = transpose(exp-normalized S) -> bf16 [Lq, Lc]
    transpose_bf16<true><<<dim3(Lq / 32, Lc / 32, Bc), 256, 0, stream>>>(
        S, q2cT, Lc, Lq, (long)Lc * Lq, (long)Lq * Lc, Fmax, Frin, Lq);

    // 6) c2q = row softmax(S) -> bf16 [Lc, Lq]
    row_softmax_bf16<<<dim3(Bc * Lc / 4), 256, 0, stream>>>(S, c2q, (long)Bc * Lc);

    // 7) transposed bf16 copies (S region now dead)
    transpose_bf16<false><<<dim3(D / 32, Lc / 32, Bc), 256, 0, stream>>>(
        context, ctxT, Lc, D, (long)Lc * D, (long)D * Lc, nullptr, nullptr, 0);
    transpose_bf16<false><<<dim3(D / 32, Lq / 32, Bc), 256, 0, stream>>>(
        query, qT, Lq, D, (long)Lq * D, (long)D * Lq, nullptr, nullptr, 0);

    // 8) G3: ctq = c2q @ qT^T; epilogue writes out[0:D]=ctx, [D:2D]=ctq, [2D:3D]=ctx*ctq
    gemm_mfma<false, 4><<<dim3(4, 16, Bc), 256, 0, stream>>>(
        c2q, nullptr, qT, nullptr, out, nullptr, nullptr,
        Lc, D, Lq, (long)Lc * Lq, (long)D * Lq, (long)Lc * 4 * D, 4 * D,
        context, nullptr, nullptr, (long)Lc * D);

    // 9) G4: Tt[b] = ctxT @ q2cT^T = (q2c^T @ ctx)^T  [D, Lq] bf16
    gemm_mfma<false, 2><<<dim3(4, 4, Bc), 256, 0, stream>>>(
        ctxT, nullptr, q2cT, nullptr, nullptr, Tt, nullptr,
        D, Lq, Lc, (long)D * Lc, (long)Lq * Lc, (long)D * Lq, Lq,
        nullptr, nullptr, nullptr, 0);

    // 10) G5: qtc = c2q @ Tt^T; epilogue writes out[3D:4D] = ctx*qtc
    gemm_mfma<false, 5><<<dim3(4, 16, Bc), 256, 0, stream>>>(
        c2q, nullptr, Tt, nullptr, out + 3 * D, nullptr, nullptr,
        Lc, D, Lq, (long)Lc * Lq, (long)D * Lq, (long)Lc * 4 * D, 4 * D,
        context, nullptr, nullptr, (long)Lc * D);
}